// Round 13
// baseline (712.669 us; speedup 1.0000x reference)
//
#include <hip/hip_runtime.h>
#include <cstdint>

#define TC 18
#define HW 180
#define EPSF 1e-5f

typedef _Float16 half8 __attribute__((ext_vector_type(8)));
typedef _Float16 half4 __attribute__((ext_vector_type(4)));
typedef float f32x4 __attribute__((ext_vector_type(4)));

// ws layout in halfs (_Float16)
#define OFF_SHB  0
#define N_SHB    (2*HW*HW*64)                  // 4,147,200
#define OFF_WSH  (N_SHB)                       // 4,147,200
#define N_WSH    (9*64*512)                    // 294,912
#define OFF_WM   (OFF_WSH + N_WSH)             // 4,442,112
#define N_WM     (36*9*64*64)                  // 1,327,104
#define OFF_W2   (OFF_WM + N_WM)               // 5,769,216
#define N_W2     (36*9*16*64)                  // 331,776
#define OFF_XH   (OFF_W2 + N_W2)               // 6,100,992
#define N_XH     ((size_t)2*HW*HW*512)         // 33,177,600 halfs (66 MB) NHWC fp16 x

// ---------------- prep: repack weights to fp16 MFMA-friendly layouts ----------
__global__ __launch_bounds__(256) void prep_kernel(
    const float* __restrict__ w_s, const float* __restrict__ w_hm1,
    const float* __restrict__ w_attr1, const float* __restrict__ w_hm2,
    const float* __restrict__ w_attr2, _Float16* __restrict__ ws) {
  int i = blockIdx.x * 256 + threadIdx.x;
  if (i < N_WSH) {
    // wsh[tap][oc][ic512]
    int ic = i & 511, oc = (i >> 9) & 63, tap = i >> 15;
    ws[OFF_WSH + i] = (_Float16)w_s[((size_t)(oc*512 + ic))*9 + tap];
    return;
  }
  i -= N_WSH;
  if (i < N_WM) {
    // wm[g][tap][oc][ic64]
    int ic = i & 63, oc = (i >> 6) & 63, tap = (i >> 12) % 9, g = i / 36864;
    float v;
    if (g < 6) v = w_hm1[((size_t)((g*64 + oc)*64 + ic))*9 + tap];
    else       v = w_attr1[((size_t)(((g-6)*64 + oc)*64 + ic))*9 + tap];
    ws[OFF_WM + i] = (_Float16)v;
    return;
  }
  i -= N_WM;
  if (i < N_W2) {
    // w2[g][tap][oc16][ic64], zero-padded oc
    int ic = i & 63, oc = (i >> 6) & 15, tap = (i >> 10) % 9, g = i / 9216;
    float v = 0.f;
    if (g < 6) { if (oc < 2) v = w_hm2[((size_t)((g*2 + oc)*64 + ic))*9 + tap]; }
    else       { if (oc < 3) v = w_attr2[((size_t)(((g-6)*3 + oc)*64 + ic))*9 + tap]; }
    ws[OFF_W2 + i] = (_Float16)v;
  }
}

// ---------------- transpose: x NCHW fp32 -> xh NHWC fp16, zeroing inactive tiles
__global__ __launch_bounds__(256) void transpose_nhwc(
    const float* __restrict__ x, const int* __restrict__ tmask,
    _Float16* __restrict__ xh) {
  int bid = blockIdx.x;
  int b = bid / (TC*TC), t = bid % (TC*TC);
  int ty = t / TC, tx = t % TC;
  int Y0 = ty*10, X0 = tx*10;
  int tid = threadIdx.x;
  _Float16* xp = xh + (size_t)b*HW*HW*512;
  bool active = tmask[b*TC*TC + t] != 0;
  if (!active) {
    half8 z;
    #pragma unroll
    for (int j = 0; j < 8; j++) z[j] = (_Float16)0.f;
    for (int i = tid; i < 6400; i += 256) {     // 100 px * 64 slots
      int px = i >> 6, s = i & 63;
      int gy = Y0 + px/10, gx = X0 + px%10;
      *(half8*)(xp + ((size_t)(gy*HW + gx))*512 + s*8) = z;
    }
    return;
  }
  __shared__ float lds[64][101];                // 25.9 KB, pad vs bank conflicts
  for (int ck = 0; ck < 8; ck++) {
    __syncthreads();
    for (int i = tid; i < 6400; i += 256) {     // coalesced read along px
      int c = i / 100, px = i % 100;
      int gy = Y0 + px/10, gx = X0 + px%10;
      lds[c][px] = x[(((size_t)b*512 + ck*64 + c)*HW + gy)*HW + gx];
    }
    __syncthreads();
    for (int i = tid; i < 800; i += 256) {      // 100 px * 8 half8-slots
      int px = i >> 3, s = i & 7;
      int gy = Y0 + px/10, gx = X0 + px%10;
      half8 hv;
      #pragma unroll
      for (int k = 0; k < 8; k++) hv[k] = (_Float16)lds[s*8 + k][px];
      *(half8*)(xp + ((size_t)(gy*HW + gx))*512 + ck*64 + s*8) = hv;
    }
  }
}

// ---- shared conv epilogue helper (BN+ReLU -> fp16 NHWC), shared by both variants
__device__ __forceinline__ void shared_epilogue(
    f32x4 (&acc)[4][2], int mh, int nh, int l15, int l4, int Y0, int X0,
    const float* g_s, const float* b_s, const float* m_s, const float* v_s,
    _Float16* shp) {
  float sc4[2][4], sh4[2][4];
  #pragma unroll
  for (int j = 0; j < 2; j++) {
    int ocb = (nh*2 + j)*16 + l4*4;
    float4 gg = *(const float4*)&g_s[ocb];
    float4 vv = *(const float4*)&v_s[ocb];
    float4 bb = *(const float4*)&b_s[ocb];
    float4 mm = *(const float4*)&m_s[ocb];
    float gA[4] = {gg.x,gg.y,gg.z,gg.w}, vA[4] = {vv.x,vv.y,vv.z,vv.w};
    float bA[4] = {bb.x,bb.y,bb.z,bb.w}, mA[4] = {mm.x,mm.y,mm.z,mm.w};
    #pragma unroll
    for (int r = 0; r < 4; r++) {
      float s = gA[r] * rsqrtf(vA[r] + EPSF);
      sc4[j][r] = s; sh4[j][r] = bA[r] - mA[r]*s;
    }
  }
  #pragma unroll
  for (int fi = 0; fi < 4; fi++) {
    int f = mh + fi*2;
    if (f < 7) {
      int p = f*16 + l15;
      if (p < 100) {
        int gy = Y0 + p/10, gx = X0 + p%10;
        _Float16* dst = shp + ((size_t)(gy*HW + gx))*64;
        #pragma unroll
        for (int j = 0; j < 2; j++) {
          int ocb = (nh*2 + j)*16 + l4*4;
          half4 hv;
          #pragma unroll
          for (int r = 0; r < 4; r++)
            hv[r] = (_Float16)fmaxf(fmaf(acc[fi][j][r], sc4[j][r], sh4[j][r]), 0.f);
          *(half4*)(dst + ocb) = hv;
        }
      }
    }
  }
}

// ---------------- shared conv 512->64 from pre-transposed NHWC fp16 (fast path)
__global__ __launch_bounds__(256, 4) void shared_conv_mfma_xh(
    const _Float16* __restrict__ xh, const int* __restrict__ tmask,
    const _Float16* __restrict__ wsh,
    const float* __restrict__ g_s, const float* __restrict__ b_s,
    const float* __restrict__ m_s, const float* __restrict__ v_s,
    _Float16* __restrict__ shb) {
  int bid = blockIdx.x;
  int b = bid / (TC*TC), t = bid % (TC*TC);
  int ty = t / TC, tx = t % TC;
  int Y0 = ty*10, X0 = tx*10;
  int tid = threadIdx.x;
  _Float16* shp = shb + (size_t)b*HW*HW*64;
  bool active = tmask[b*TC*TC + t] != 0;
  if (!active) {
    for (int i = tid; i < 1600; i += 256) {
      int px = i >> 4, q = i & 15;
      int gy = Y0 + px/10, gx = X0 + px%10;
      *(float2*)(shp + ((size_t)(gy*HW + gx))*64 + q*4) = make_float2(0.f, 0.f);
    }
    return;
  }
  const _Float16* xhp = xh + (size_t)b*HW*HW*512;
  __shared__ _Float16 sm[144*64];
  int lane = tid & 63, w = tid >> 6;
  int mh = w >> 1, nh = w & 1;
  int l15 = lane & 15, l4 = lane >> 4;
  int r0[4];
  #pragma unroll
  for (int fi = 0; fi < 4; fi++) {
    int f = mh + fi*2;
    int p = f*16 + l15; if (p > 99) p = 99;
    r0[fi] = (p/10)*12 + (p%10);
  }
  f32x4 acc[4][2];
  #pragma unroll
  for (int fi = 0; fi < 4; fi++)
    #pragma unroll
    for (int j = 0; j < 2; j++) acc[fi][j] = (f32x4)0.f;

  for (int ck = 0; ck < 8; ck++) {
    __syncthreads();
    for (int i = tid; i < 1152; i += 256) {     // 144 px * 8 slots, vector loads
      int px = i >> 3, s8 = i & 7;
      int ry = px/12, rx = px%12;
      int gy = Y0-1+ry, gx = X0-1+rx;
      half8 hv;
      if (gy >= 0 && gy < HW && gx >= 0 && gx < HW)
        hv = *(const half8*)(xhp + ((size_t)(gy*HW + gx))*512 + ck*64 + s8*8);
      else {
        #pragma unroll
        for (int j = 0; j < 8; j++) hv[j] = (_Float16)0.f;
      }
      *(half8*)((char*)sm + px*128 + (((s8 ^ px) & 7)<<4)) = hv;
    }
    __syncthreads();
    for (int tap = 0; tap < 9; tap++) {
      int radd = (tap/3)*12 + (tap%3);
      #pragma unroll
      for (int ks = 0; ks < 2; ks++) {
        half8 bf[2];
        #pragma unroll
        for (int j = 0; j < 2; j++) {
          int oc = (nh*2 + j)*16 + l15;
          bf[j] = *(const half8*)(wsh + (size_t)(tap*64 + oc)*512 + ck*64 + ks*32 + l4*8);
        }
        #pragma unroll
        for (int fi = 0; fi < 4; fi++) {
          int f = mh + fi*2;
          if (f < 7) {
            int r = r0[fi] + radd;
            half8 af = *(const half8*)((const char*)sm + (r<<7) + ((((ks*4 + l4) ^ r) & 7)<<4));
            acc[fi][0] = __builtin_amdgcn_mfma_f32_16x16x32_f16(bf[0], af, acc[fi][0], 0, 0, 0);
            acc[fi][1] = __builtin_amdgcn_mfma_f32_16x16x32_f16(bf[1], af, acc[fi][1], 0, 0, 0);
          }
        }
      }
    }
  }
  shared_epilogue(acc, mh, nh, l15, l4, Y0, X0, g_s, b_s, m_s, v_s, shp);
}

// ---------------- shared conv 512->64 from NCHW fp32 (fallback, proven R10 path)
__global__ __launch_bounds__(256, 4) void shared_conv_mfma_nchw(
    const float* __restrict__ x, const int* __restrict__ tmask,
    const _Float16* __restrict__ wsh,
    const float* __restrict__ g_s, const float* __restrict__ b_s,
    const float* __restrict__ m_s, const float* __restrict__ v_s,
    _Float16* __restrict__ shb) {
  int bid = blockIdx.x;
  int b = bid / (TC*TC), t = bid % (TC*TC);
  int ty = t / TC, tx = t % TC;
  int Y0 = ty*10, X0 = tx*10;
  int tid = threadIdx.x;
  _Float16* shp = shb + (size_t)b*HW*HW*64;
  bool active = tmask[b*TC*TC + t] != 0;
  if (!active) {
    for (int i = tid; i < 1600; i += 256) {
      int px = i >> 4, q = i & 15;
      int gy = Y0 + px/10, gx = X0 + px%10;
      *(float2*)(shp + ((size_t)(gy*HW + gx))*64 + q*4) = make_float2(0.f, 0.f);
    }
    return;
  }
  int nact = 0;
  #pragma unroll
  for (int dy = 0; dy < 3; dy++)
    #pragma unroll
    for (int dx = 0; dx < 3; dx++) {
      int tyy = ty+dy-1, txx = tx+dx-1;
      int a = (tyy>=0 && tyy<TC && txx>=0 && txx<TC) ? tmask[b*TC*TC + tyy*TC + txx] : 0;
      nact |= (a != 0) << (dy*3+dx);
    }
  __shared__ _Float16 sm[144*64];
  int lane = tid & 63, w = tid >> 6;
  int mh = w >> 1, nh = w & 1;
  int l15 = lane & 15, l4 = lane >> 4;
  int r0[4];
  #pragma unroll
  for (int fi = 0; fi < 4; fi++) {
    int f = mh + fi*2;
    int p = f*16 + l15; if (p > 99) p = 99;
    r0[fi] = (p/10)*12 + (p%10);
  }
  f32x4 acc[4][2];
  #pragma unroll
  for (int fi = 0; fi < 4; fi++)
    #pragma unroll
    for (int j = 0; j < 2; j++) acc[fi][j] = (f32x4)0.f;

  for (int ck = 0; ck < 8; ck++) {
    __syncthreads();
    for (int i = tid; i < 1152; i += 256) {     // 144 px * 8 slots (scalar loads)
      int px = i % 144, s8 = i / 144;
      int ry = px/12, rx = px%12;
      int gy = Y0-1+ry, gx = X0-1+rx;
      int selr = (ry==0)?0:((ry<=10)?1:2);
      int selc = (rx==0)?0:((rx<=10)?1:2);
      bool ok = (gy>=0 && gy<HW && gx>=0 && gx<HW) && ((nact>>(selr*3+selc))&1);
      half8 hv;
      #pragma unroll
      for (int j = 0; j < 8; j++) hv[j] = (_Float16)0.f;
      if (ok) {
        const float* xp = x + (((size_t)b*512 + ck*64 + s8*8)*HW + gy)*HW + gx;
        #pragma unroll
        for (int j = 0; j < 8; j++) hv[j] = (_Float16)xp[(size_t)j*HW*HW];
      }
      *(half8*)((char*)sm + px*128 + (((s8 ^ (px&7)) & 7)<<4)) = hv;
    }
    __syncthreads();
    for (int tap = 0; tap < 9; tap++) {
      int radd = (tap/3)*12 + (tap%3);
      #pragma unroll
      for (int ks = 0; ks < 2; ks++) {
        half8 bf[2];
        #pragma unroll
        for (int j = 0; j < 2; j++) {
          int oc = (nh*2 + j)*16 + l15;
          bf[j] = *(const half8*)(wsh + (size_t)(tap*64 + oc)*512 + ck*64 + ks*32 + l4*8);
        }
        #pragma unroll
        for (int fi = 0; fi < 4; fi++) {
          int f = mh + fi*2;
          if (f < 7) {
            int r = r0[fi] + radd;
            half8 af = *(const half8*)((const char*)sm + (r<<7) + ((((ks*4 + l4) ^ r) & 7)<<4));
            acc[fi][0] = __builtin_amdgcn_mfma_f32_16x16x32_f16(bf[0], af, acc[fi][0], 0, 0, 0);
            acc[fi][1] = __builtin_amdgcn_mfma_f32_16x16x32_f16(bf[1], af, acc[fi][1], 0, 0, 0);
          }
        }
      }
    }
  }
  shared_epilogue(acc, mh, nh, l15, l4, Y0, X0, g_s, b_s, m_s, v_s, shp);
}

// -------- branch: block = (tile, group-pair); wave = (M-half) x (one group, 64 oc)
// mid conv 64->64 per group + grouped 64->{2,3}; h1 aliases dead input tile.
__global__ __launch_bounds__(256, 3) void branch_conv_mfma(
    const _Float16* __restrict__ shb, const int* __restrict__ tmask,
    const _Float16* __restrict__ wm, const _Float16* __restrict__ w2,
    const float* __restrict__ g_h, const float* __restrict__ b_h,
    const float* __restrict__ m_h, const float* __restrict__ v_h,
    const float* __restrict__ g_a, const float* __restrict__ b_a,
    const float* __restrict__ m_a, const float* __restrict__ v_a,
    const float* __restrict__ bias_hm, const float* __restrict__ bias_attr,
    float* __restrict__ out) {
  int bid = blockIdx.x;
  int g2 = bid % 18;                 // group pair id: groups g2*2, g2*2+1
  int t = bid / 18;
  int b = t / (TC*TC); t %= (TC*TC);
  int ty = t / TC, tx = t % TC;
  int Y0 = ty*10, X0 = tx*10;
  int tid = threadIdx.x;
  bool active = tmask[b*TC*TC + ty*TC + tx] != 0;
  if (!active) {
    if (tid < 100) {
      int py = tid/10, pxx = tid%10;
      #pragma unroll
      for (int gi = 0; gi < 2; gi++) {
        int g = g2*2 + gi;
        int Oc = (g < 6) ? 2 : 3;
        int cobase = (g < 6) ? g*2 : 12 + (g-6)*3;
        for (int o = 0; o < Oc; o++)
          out[(((size_t)b*102 + cobase + o)*HW + (Y0+py))*HW + (X0+pxx)] = 0.f;
      }
    }
    return;
  }
  int nact = 0;
  #pragma unroll
  for (int dy = 0; dy < 3; dy++)
    #pragma unroll
    for (int dx = 0; dx < 3; dx++) {
      int tyy = ty+dy-1, txx = tx+dx-1;
      int a = (tyy>=0 && tyy<TC && txx>=0 && txx<TC) ? tmask[b*TC*TC + tyy*TC + txx] : 0;
      nact |= (a != 0) << (dy*3+dx);
    }
  // input: rows 0..195 (196*128B); h0: rows 196..339; h1 aliases input rows 0..143
  __shared__ _Float16 sm[(196 + 144)*64];   // 43520 B
  const _Float16* shp = shb + (size_t)b*HW*HW*64;
  int lane = tid & 63, w = tid >> 6;
  int gi = w & 1, m = w >> 1;
  int g = g2*2 + gi;
  int l15 = lane & 15, l4 = lane >> 4;

  // stage 14x14x64 fp16 tile (swizzled)
  for (int i = tid; i < 1568; i += 256) {       // 196 px * 8 slots
    int px = i >> 3, s8 = i & 7;
    int ry = px/14, rx = px%14;
    int gy = Y0-2+ry, gx = X0-2+rx;
    half8 hv;
    if (gy>=0 && gy<HW && gx>=0 && gx<HW)
      hv = *(const half8*)(shp + ((size_t)(gy*HW + gx))*64 + s8*8);
    else {
      #pragma unroll
      for (int j = 0; j < 8; j++) hv[j] = (_Float16)0.f;
    }
    *(half8*)((char*)sm + px*128 + (((s8 ^ px) & 7)<<4)) = hv;
  }
  __syncthreads();

  // mid conv for group gi: Mfrags gf = m*5 + fi (gf<9), N = 64 oc (4 Nfrags)
  int r0[5];
  #pragma unroll
  for (int fi = 0; fi < 5; fi++) {
    int gf = m*5 + fi;
    int p = gf*16 + l15; if (p > 143) p = 143;
    r0[fi] = (p/12)*14 + (p%12);
  }
  f32x4 acc[5][4];
  #pragma unroll
  for (int fi = 0; fi < 5; fi++)
    #pragma unroll
    for (int nf = 0; nf < 4; nf++) acc[fi][nf] = (f32x4)0.f;

  const _Float16* wmg = wm + (size_t)g*9*64*64;
  for (int tap = 0; tap < 9; tap++) {
    int radd = (tap/3)*14 + (tap%3);
    #pragma unroll
    for (int ks = 0; ks < 2; ks++) {
      half8 bf[4];
      #pragma unroll
      for (int nf = 0; nf < 4; nf++)
        bf[nf] = *(const half8*)(wmg + (size_t)(tap*64 + nf*16 + l15)*64 + ks*32 + l4*8);
      #pragma unroll
      for (int fi = 0; fi < 5; fi++) {
        int gf = m*5 + fi;
        if (gf < 9) {
          int r = r0[fi] + radd;
          half8 af = *(const half8*)((const char*)sm + (r<<7) + ((((ks*4 + l4) ^ r) & 7)<<4));
          #pragma unroll
          for (int nf = 0; nf < 4; nf++)
            acc[fi][nf] = __builtin_amdgcn_mfma_f32_16x16x32_f16(bf[nf], af, acc[fi][nf], 0, 0, 0);
        }
      }
    }
  }

  // BN + ReLU + pixel mask -> h (fp16, swizzled rows of 128B)
  {
    int cbase = (g < 6) ? g*64 : (g-6)*64;
    const float* GG = (g < 6) ? g_h : g_a;
    const float* VV = (g < 6) ? v_h : v_a;
    const float* BB = (g < 6) ? b_h : b_a;
    const float* MM = (g < 6) ? m_h : m_a;
    float sc4[4][4], sh4[4][4];
    #pragma unroll
    for (int nf = 0; nf < 4; nf++) {
      int c = cbase + nf*16 + l4*4;
      float4 gg = *(const float4*)&GG[c];
      float4 vv = *(const float4*)&VV[c];
      float4 bb = *(const float4*)&BB[c];
      float4 mm = *(const float4*)&MM[c];
      float gA[4] = {gg.x,gg.y,gg.z,gg.w}, vA[4] = {vv.x,vv.y,vv.z,vv.w};
      float bA[4] = {bb.x,bb.y,bb.z,bb.w}, mA[4] = {mm.x,mm.y,mm.z,mm.w};
      #pragma unroll
      for (int r = 0; r < 4; r++) {
        float s = gA[r] * rsqrtf(vA[r] + EPSF);
        sc4[nf][r] = s; sh4[nf][r] = bA[r] - mA[r]*s;
      }
    }
    #pragma unroll
    for (int phase = 0; phase < 2; phase++) {
      if (gi == phase) {
        _Float16* hb = (phase == 0) ? (_Float16*)sm + 196*64 : (_Float16*)sm;
        #pragma unroll
        for (int fi = 0; fi < 5; fi++) {
          int gf = m*5 + fi;
          if (gf < 9) {
            int px = gf*16 + l15;                 // 0..143
            int hy = px/12, hx = px - hy*12;
            int selr = (hy==0)?0:((hy<=10)?1:2);
            int selc = (hx==0)?0:((hx<=10)?1:2);
            bool ok = (nact>>(selr*3+selc)) & 1;
            #pragma unroll
            for (int nf = 0; nf < 4; nf++) {
              int ocb = nf*16 + l4*4;
              half4 hv;
              #pragma unroll
              for (int r = 0; r < 4; r++) {
                float v = ok ? fmaxf(fmaf(acc[fi][nf][r], sc4[nf][r], sh4[nf][r]), 0.f) : 0.f;
                hv[r] = (_Float16)v;
              }
              *(half4*)((char*)hb + (px<<7) + ((((ocb>>3) ^ px) & 7)<<4) + (ocb&7)*2) = hv;
            }
          }
        }
      }
      __syncthreads();
    }
  }

  // out conv: wave (m, gi) -> group gi, Mfrags f = m*4 + fi (f<7), N = 16 (Oc used)
  const _Float16* hb = (gi == 0) ? (const _Float16*)sm + 196*64 : (const _Float16*)sm;
  int r0b[4];
  #pragma unroll
  for (int fi = 0; fi < 4; fi++) {
    int f = m*4 + fi;
    int p = f*16 + l15; if (p > 99) p = 99;
    r0b[fi] = (p/10)*12 + (p%10);
  }
  f32x4 acc2[4];
  #pragma unroll
  for (int fi = 0; fi < 4; fi++) acc2[fi] = (f32x4)0.f;
  const _Float16* w2g = w2 + (size_t)g*9*16*64;
  for (int tap = 0; tap < 9; tap++) {
    int radd = (tap/3)*12 + (tap%3);
    #pragma unroll
    for (int ks = 0; ks < 2; ks++) {
      half8 bf = *(const half8*)(w2g + (size_t)(tap*16 + l15)*64 + ks*32 + l4*8);
      #pragma unroll
      for (int fi = 0; fi < 4; fi++) {
        int f = m*4 + fi;
        if (f < 7) {
          int r = r0b[fi] + radd;
          half8 af = *(const half8*)((const char*)hb + (r<<7) + ((((ks*4 + l4) ^ r) & 7)<<4));
          acc2[fi] = __builtin_amdgcn_mfma_f32_16x16x32_f16(bf, af, acc2[fi], 0, 0, 0);
        }
      }
    }
  }
  // store: lane l4==0 holds oc = reg (0..3), px = f*16 + l15 (row-coalesced)
  int Oc = (g < 6) ? 2 : 3;
  int cobase = (g < 6) ? g*2 : 12 + (g-6)*3;
  float bo[3];
  #pragma unroll
  for (int o = 0; o < 3; o++)
    bo[o] = (o < Oc) ? ((g < 6) ? bias_hm[g*2 + o] : bias_attr[(g-6)*3 + o]) : 0.f;
  #pragma unroll
  for (int fi = 0; fi < 4; fi++) {
    int f = m*4 + fi;
    int p = f*16 + l15;
    if (f < 7 && l4 == 0 && p < 100) {
      int gy = Y0 + p/10, gx = X0 + p%10;
      float* op = out + (((size_t)b*102 + cobase)*HW + gy)*HW + gx;
      #pragma unroll
      for (int o = 0; o < 3; o++)
        if (o < Oc) op[(size_t)o*HW*HW] = acc2[fi][o] + bo[o];
    }
  }
}

extern "C" void kernel_launch(void* const* d_in, const int* in_sizes, int n_in,
                              void* d_out, int out_size, void* d_ws, size_t ws_size,
                              hipStream_t stream) {
  const float* x        = (const float*)d_in[0];
  const int*   tmask    = (const int*)  d_in[1];
  const float* w_s      = (const float*)d_in[2];
  const float* g_s      = (const float*)d_in[3];
  const float* b_s      = (const float*)d_in[4];
  const float* m_s      = (const float*)d_in[5];
  const float* v_s      = (const float*)d_in[6];
  const float* w_hm1    = (const float*)d_in[7];
  const float* g_h      = (const float*)d_in[8];
  const float* b_h      = (const float*)d_in[9];
  const float* m_h      = (const float*)d_in[10];
  const float* v_h      = (const float*)d_in[11];
  const float* w_hm2    = (const float*)d_in[12];
  const float* bias_hm  = (const float*)d_in[13];
  const float* w_attr1  = (const float*)d_in[14];
  const float* g_a      = (const float*)d_in[15];
  const float* b_a      = (const float*)d_in[16];
  const float* m_a      = (const float*)d_in[17];
  const float* v_a      = (const float*)d_in[18];
  const float* w_attr2  = (const float*)d_in[19];
  const float* bias_attr= (const float*)d_in[20];
  _Float16* ws = (_Float16*)d_ws;
  float* out = (float*)d_out;

  int prep_total = N_WSH + N_WM + N_W2;
  prep_kernel<<<(prep_total + 255)/256, 256, 0, stream>>>(
      w_s, w_hm1, w_attr1, w_hm2, w_attr2, ws);

  size_t need_bytes = ((size_t)OFF_XH + N_XH) * sizeof(_Float16);  // ~78.6 MB
  if (ws_size >= need_bytes) {
    transpose_nhwc<<<2*TC*TC, 256, 0, stream>>>(x, tmask, ws + OFF_XH);
    shared_conv_mfma_xh<<<2*TC*TC, 256, 0, stream>>>(
        ws + OFF_XH, tmask, ws + OFF_WSH, g_s, b_s, m_s, v_s, ws + OFF_SHB);
  } else {
    shared_conv_mfma_nchw<<<2*TC*TC, 256, 0, stream>>>(
        x, tmask, ws + OFF_WSH, g_s, b_s, m_s, v_s, ws + OFF_SHB);
  }
  branch_conv_mfma<<<2*TC*TC*18, 256, 0, stream>>>(
      ws + OFF_SHB, tmask, ws + OFF_WM, ws + OFF_W2,
      g_h, b_h, m_h, v_h, g_a, b_a, m_a, v_a, bias_hm, bias_attr, out);
}